// Round 6
// baseline (2042.349 us; speedup 1.0000x reference)
//
#include <hip/hip_runtime.h>

typedef __attribute__((ext_vector_type(8))) short s16x8;
typedef __attribute__((ext_vector_type(4))) float f32x4;
typedef __attribute__((ext_vector_type(16))) float f32x16;

#define BATCH 32768
#define LSEQ 128
// 32x32 A-frag store: [8 triples][4 gates(r,z,hn,in)][17 ks][512 shorts]
#define W32_SHORTS (8 * 4 * 17 * 512)                 // 278528
#define WFC_SHORTS 4096
#define XT_OFF_BYTES ((W32_SHORTS + WFC_SHORTS) * 2)  // 565248
#define WS_NEED_XT (XT_OFF_BYTES + BATCH * LSEQ * 4)  // ~17.3 MB

#define HROW 264                       // padded h row stride (shorts): 256 + 8
#define HBUF_S (128 * HROW)            // 33792 shorts = 67584 B per buffer
#define LDS_BYTES (2 * HBUF_S * 2)     // 135168 B

#define L2E 1.4426950408889634f
#define LN2 0.6931471805599453f

#define MFMA32(A, B, C) __builtin_amdgcn_mfma_f32_32x32x16_bf16(A, B, C, 0, 0, 0)

__device__ __forceinline__ unsigned short f2b(float f) {
  unsigned u = __float_as_uint(f);
  u += 0x7FFFu + ((u >> 16) & 1u);     // RNE bf16
  return (unsigned short)(u >> 16);
}

__device__ __forceinline__ float exp2n(float x) { float r; asm("v_exp_f32 %0, -%1" : "=v"(r) : "v"(x)); return r; }
__device__ __forceinline__ float exp2p(float x) { float r; asm("v_exp_f32 %0, %1" : "=v"(r) : "v"(x)); return r; }
__device__ __forceinline__ float rcp_(float x)  { float r; asm("v_rcp_f32 %0, %1" : "=v"(r) : "v"(x)); return r; }
__device__ __forceinline__ float log2_(float x) { float r; asm("v_log_f32 %0, %1" : "=v"(r) : "v"(x)); return r; }
__device__ __forceinline__ unsigned cvtpk(float lo, float hi) {
  unsigned r; asm("v_cvt_pk_bf16_f32 %0, %1, %2" : "=v"(r) : "v"(lo), "v"(hi)); return r;
}

// Pack weights into 32x32x16 MFMA A-fragment order (NO scale folding):
// frag(tr, g, ks): A-row j = g*256 + tr*32 + (lane&31)  [g=3: j = 512 + ...]
// k = ks*16 + (lane>>5)*8 + e   (ks<16);  ks==16 is the aug tile:
// k256 = x-coeff, k257 = bias, rest 0.
__global__ void gru_prep(const float* __restrict__ Wih, const float* __restrict__ Whh,
                         const float* __restrict__ bih, const float* __restrict__ bhh,
                         const float* __restrict__ Wfc,
                         unsigned short* __restrict__ wfrag,
                         unsigned short* __restrict__ wfc16) {
  int t = blockIdx.x * 256 + threadIdx.x;
  if (t < W32_SHORTS) {
    int e = t & 7, lane = (t >> 3) & 63, frag = t >> 9;
    int ks = frag % 17, g = (frag / 17) & 3, tr = frag / 68;
    int l31 = lane & 31, hh = lane >> 5;
    int k = (ks < 16) ? ks * 16 + hh * 8 + e : 256 + hh * 8 + e;
    float val = 0.f;
    if (g < 3) {
      int j = g * 256 + tr * 32 + l31;
      if (k < 256) val = Whh[j * 256 + k];
      else if (k == 256) val = (g < 2) ? Wih[j] : 0.f;
      else if (k == 257) val = (g < 2) ? (bih[j] + bhh[j]) : bhh[j];
    } else if (ks == 16) {             // i_n tile: aug only
      int j = 512 + tr * 32 + l31;
      if (k == 256) val = Wih[j];
      else if (k == 257) val = bih[j];
    }
    wfrag[t] = f2b(val);
  } else if (t < W32_SHORTS + WFC_SHORTS) {   // W_fc bf16 [16][256] row-major
    int t2 = t - W32_SHORTS;
    wfc16[t2] = f2b(Wfc[t2]);
  }
}

__global__ void x_transpose(const int* __restrict__ x, int* __restrict__ xT) {
  __shared__ int tile[32][33];
  int l0 = blockIdx.x * 32, b0 = blockIdx.y * 32;
  for (int r = threadIdx.y; r < 32; r += 8)
    tile[r][threadIdx.x] = x[(b0 + r) * LSEQ + l0 + threadIdx.x];
  __syncthreads();
  for (int r = threadIdx.y; r < 32; r += 8)
    xT[(l0 + r) * BATCH + b0 + threadIdx.x] = tile[threadIdx.x][r];
}

template <int XT>
__global__ __attribute__((amdgpu_waves_per_eu(2, 2))) __launch_bounds__(512)
void gru_main(const int* __restrict__ x, const int* __restrict__ xTr,
              const unsigned short* __restrict__ wfrag,
              const unsigned short* __restrict__ wfc16,
              const float* __restrict__ bfc, float* __restrict__ out) {
  extern __shared__ unsigned short sm[];

  const int tid = threadIdx.x;
  const int lane = tid & 63;
  const int wv = tid >> 6;       // wave 0..7 = j-triple
  const int tr = wv;
  const int l31 = lane & 31;     // batch col within 32-group / A-row within tile
  const int hh = lane >> 5;      // k-half
  const int q = lane >> 4;       // FC 16x16 coords
  const int b = lane & 15;
  const int bbase = blockIdx.x * 128;

  { // zero h buffer 0 (buffer 1 fully written in step 0 before any read)
    unsigned int* p = (unsigned int*)sm;
    for (int r = tid; r < HBUF_S / 2; r += 512) p[r] = 0u;
  }

  float bfc4[4];
#pragma unroll
  for (int r = 0; r < 4; ++r) bfc4[r] = bfc[q * 4 + r];

  const int offR = ((tr * 4 + 0) * 17) * 512 + lane * 8;
  const int offZ = ((tr * 4 + 1) * 17) * 512 + lane * 8;
  const int offH = ((tr * 4 + 2) * 17) * 512 + lane * 8;
  const int offI = ((tr * 4 + 3) * 17) * 512 + lane * 8;
  const int offFC = b * 256 + q * 8;

  const f32x16 z16 = {0, 0, 0, 0, 0, 0, 0, 0, 0, 0, 0, 0, 0, 0, 0, 0};

  float lp = 0.f;
  __syncthreads();

#pragma unroll 1
  for (int i = 0; i < LSEQ; ++i) {
    const unsigned short* rdb = sm + (i & 1) * HBUF_S;
    unsigned short* wrb = sm + ((i & 1) ^ 1) * HBUF_S;

    // launder weight pointers: keep per-step loads from being hoisted/staged
    unsigned long wfu = (unsigned long)wfrag;
    asm volatile("" : "+s"(wfu));
    const unsigned short* wfp = (const unsigned short*)wfu;
    const unsigned short* fR = wfp + offR;
    const unsigned short* fZ = wfp + offZ;
    const unsigned short* fH = wfp + offH;
    const unsigned short* fI = wfp + offI;
    unsigned long wcu = (unsigned long)wfc16;
    asm volatile("" : "+s"(wcu));
    const unsigned short* fFC = (const unsigned short*)wcu + offFC;

#pragma unroll
    for (int p = 0; p < 2; ++p) {
      const int b0 = 2 * p, b1 = 2 * p + 1;

      float xv0, xv1;
      if (XT) {
        xv0 = (i > 0) ? (float)xTr[(i - 1) * BATCH + bbase + b0 * 32 + l31] : 0.f;
        xv1 = (i > 0) ? (float)xTr[(i - 1) * BATCH + bbase + b1 * 32 + l31] : 0.f;
      } else {
        xv0 = (i > 0) ? (float)x[(bbase + b0 * 32 + l31) * LSEQ + i - 1] : 0.f;
        xv1 = (i > 0) ? (float)x[(bbase + b1 * 32 + l31) * LSEQ + i - 1] : 0.f;
      }
      // aug B-frags: k256 = bf16(x) (exact for 0..15), k257 = 1.0; hh=1 half zero
      union { unsigned u[4]; s16x8 v; } xf0, xf1;
      xf0.u[0] = (hh == 0) ? ((__float_as_uint(xv0) >> 16) | 0x3F800000u) : 0u;
      xf0.u[1] = xf0.u[2] = xf0.u[3] = 0u;
      xf1.u[0] = (hh == 0) ? ((__float_as_uint(xv1) >> 16) | 0x3F800000u) : 0u;
      xf1.u[1] = xf1.u[2] = xf1.u[3] = 0u;

      // aug A-frags initialize accumulators (C = 0): gi + bias done here
      s16x8 gR = *(const s16x8*)(fR + 16 * 512);
      s16x8 gZ = *(const s16x8*)(fZ + 16 * 512);
      s16x8 gH = *(const s16x8*)(fH + 16 * 512);
      s16x8 gI = *(const s16x8*)(fI + 16 * 512);
      f32x16 R0 = MFMA32(gR, xf0.v, z16), R1 = MFMA32(gR, xf1.v, z16);
      f32x16 Z0 = MFMA32(gZ, xf0.v, z16), Z1 = MFMA32(gZ, xf1.v, z16);
      f32x16 H0 = MFMA32(gH, xf0.v, z16), H1 = MFMA32(gH, xf1.v, z16);
      f32x16 I0 = MFMA32(gI, xf0.v, z16), I1 = MFMA32(gI, xf1.v, z16);

      // preload ks pair 0
      s16x8 c0r = *(const s16x8*)(fR + 0 * 512);
      s16x8 c0z = *(const s16x8*)(fZ + 0 * 512);
      s16x8 c0h = *(const s16x8*)(fH + 0 * 512);
      s16x8 c1r = *(const s16x8*)(fR + 1 * 512);
      s16x8 c1z = *(const s16x8*)(fZ + 1 * 512);
      s16x8 c1h = *(const s16x8*)(fH + 1 * 512);

      const unsigned short* r0b = rdb + (b0 * 32 + l31) * HROW;
      const unsigned short* r1b = rdb + (b1 * 32 + l31) * HROW;

#pragma unroll
      for (int it = 0; it < 8; ++it) {
        s16x8 n0r, n0z, n0h, n1r, n1z, n1h;
        if (it < 7) {   // depth-1 prefetch of the next ks pair (6 frags)
          n0r = *(const s16x8*)(fR + (2 * it + 2) * 512);
          n0z = *(const s16x8*)(fZ + (2 * it + 2) * 512);
          n0h = *(const s16x8*)(fH + (2 * it + 2) * 512);
          n1r = *(const s16x8*)(fR + (2 * it + 3) * 512);
          n1z = *(const s16x8*)(fZ + (2 * it + 3) * 512);
          n1h = *(const s16x8*)(fH + (2 * it + 3) * 512);
        }
        {
          const s16x8 hA = *(const s16x8*)&r0b[16 * (2 * it) + 8 * hh];
          const s16x8 hB = *(const s16x8*)&r1b[16 * (2 * it) + 8 * hh];
          R0 = MFMA32(c0r, hA, R0); Z0 = MFMA32(c0z, hA, Z0); H0 = MFMA32(c0h, hA, H0);
          R1 = MFMA32(c0r, hB, R1); Z1 = MFMA32(c0z, hB, Z1); H1 = MFMA32(c0h, hB, H1);
        }
        {
          const s16x8 hA = *(const s16x8*)&r0b[16 * (2 * it + 1) + 8 * hh];
          const s16x8 hB = *(const s16x8*)&r1b[16 * (2 * it + 1) + 8 * hh];
          R0 = MFMA32(c1r, hA, R0); Z0 = MFMA32(c1z, hA, Z0); H0 = MFMA32(c1h, hA, H0);
          R1 = MFMA32(c1r, hB, R1); Z1 = MFMA32(c1z, hB, Z1); H1 = MFMA32(c1h, hB, H1);
        }
        if (it < 7) { c0r = n0r; c0z = n0z; c0h = n0h; c1r = n1r; c1z = n1z; c1h = n1h; }
      }

      // epilogue: gates in f32, apply L2E here (weights unscaled), write h_i
      auto epilogue = [&](int bg, const f32x16& R, const f32x16& Zg,
                          const f32x16& Hg, const f32x16& Ig) {
        const int hrow = bg * 32 + l31;
        const unsigned short* hpb = rdb + hrow * HROW;
        unsigned short* hwb = wrb + hrow * HROW;
#pragma unroll
        for (int rq = 0; rq < 4; ++rq) {
          const int col = tr * 32 + 4 * hh + 8 * rq;
          const uint2 hp = *(const uint2*)&hpb[col];
          const float hpv[4] = {
              __uint_as_float(hp.x << 16), __uint_as_float(hp.x & 0xFFFF0000u),
              __uint_as_float(hp.y << 16), __uint_as_float(hp.y & 0xFFFF0000u)};
          float hv[4];
#pragma unroll
          for (int e2 = 0; e2 < 4; ++e2) {
            const int idx = rq * 4 + e2;
            float rr = rcp_(1.f + exp2n(L2E * R[idx]));     // sigmoid
            float zz = rcp_(1.f + exp2n(L2E * Zg[idx]));
            float y  = fmaf(rr, Hg[idx], Ig[idx]);          // i_n + r*h_n
            float u  = rcp_(1.f + exp2p((2.f * L2E) * y));
            float nn = fmaf(-2.f, u, 1.f);                  // tanh
            hv[e2] = fmaf(zz, hpv[e2] - nn, nn);            // (1-z)*n + z*h
          }
          *(uint2*)&hwb[col] = make_uint2(cvtpk(hv[0], hv[1]), cvtpk(hv[2], hv[3]));
        }
      };
      epilogue(b0, R0, Z0, H0, I0);
      epilogue(b1, R1, Z1, H1, I1);
    }

    __syncthreads();   // h_i fully visible; rd buffer is dead after this

    { // FC (16x16x32) + log_softmax + gather; wave wv handles batch tile wv
      const int lrow = wv * 16 + b;
      const int grow = bbase + lrow;
      f32x4 fa = {bfc4[0], bfc4[1], bfc4[2], bfc4[3]};
      const unsigned short* hbb = wrb + lrow * HROW;
#pragma unroll
      for (int ks = 0; ks < 8; ++ks) {
        s16x8 wf = *(const s16x8*)(fFC + 32 * ks);
        s16x8 hb = *(const s16x8*)&hbb[32 * ks + 8 * q];
        fa = __builtin_amdgcn_mfma_f32_16x16x32_bf16(wf, hb, fa, 0, 0, 0);
      }
      int tgt = XT ? xTr[i * BATCH + grow] : x[grow * LSEQ + i];
      float l0 = fa[0], l1 = fa[1], l2 = fa[2], l3 = fa[3];
      float mx = fmaxf(fmaxf(l0, l1), fmaxf(l2, l3));
      mx = fmaxf(mx, __shfl_xor(mx, 16));
      mx = fmaxf(mx, __shfl_xor(mx, 32));
      float se = exp2p(L2E * (l0 - mx)) + exp2p(L2E * (l1 - mx)) +
                 exp2p(L2E * (l2 - mx)) + exp2p(L2E * (l3 - mx));
      se += __shfl_xor(se, 16);
      se += __shfl_xor(se, 32);
      float v01 = (tgt & 1) ? l1 : l0;
      float v23 = (tgt & 1) ? l3 : l2;
      float vs = (tgt & 2) ? v23 : v01;
      float contrib = (q == (tgt >> 2)) ? vs : 0.f;
      contrib += __shfl_xor(contrib, 16);
      contrib += __shfl_xor(contrib, 32);
      lp += contrib - mx - LN2 * log2_(se);
    }
  }

  if (q == 0) out[bbase + wv * 16 + b] = lp;
}

extern "C" void kernel_launch(void* const* d_in, const int* in_sizes, int n_in,
                              void* d_out, int out_size, void* d_ws, size_t ws_size,
                              hipStream_t stream) {
  (void)in_sizes; (void)n_in; (void)out_size;
  const int*   x   = (const int*)d_in[0];
  const float* Wih = (const float*)d_in[1];
  const float* Whh = (const float*)d_in[2];
  const float* bih = (const float*)d_in[3];
  const float* bhh = (const float*)d_in[4];
  const float* Wfc = (const float*)d_in[5];
  const float* bfc = (const float*)d_in[6];
  float* out = (float*)d_out;

  unsigned short* wfrag = (unsigned short*)d_ws;
  unsigned short* wfc16 = wfrag + W32_SHORTS;
  int* xT = (int*)((char*)d_ws + XT_OFF_BYTES);

  gru_prep<<<dim3((W32_SHORTS + WFC_SHORTS) / 256), dim3(256), 0, stream>>>(
      Wih, Whh, bih, bhh, Wfc, wfrag, wfc16);

  if (ws_size >= (size_t)WS_NEED_XT) {
    x_transpose<<<dim3(LSEQ / 32, BATCH / 32), dim3(32, 8), 0, stream>>>(x, xT);
    hipFuncSetAttribute((const void*)gru_main<1>,
                        hipFuncAttributeMaxDynamicSharedMemorySize, LDS_BYTES);
    gru_main<1><<<dim3(256), dim3(512), LDS_BYTES, stream>>>(x, xT, wfrag, wfc16, bfc, out);
  } else {
    hipFuncSetAttribute((const void*)gru_main<0>,
                        hipFuncAttributeMaxDynamicSharedMemorySize, LDS_BYTES);
    gru_main<0><<<dim3(256), dim3(512), LDS_BYTES, stream>>>(x, x, wfrag, wfc16, bfc, out);
  }
}

// Round 7
// 2025.996 us; speedup vs baseline: 1.0081x; 1.0081x over previous
//
#include <hip/hip_runtime.h>

typedef __attribute__((ext_vector_type(8))) short s16x8;
typedef __attribute__((ext_vector_type(4))) float f32x4;

#define BATCH 32768
#define LSEQ 128
#define NJT 16
#define NFRAG 28                           // frags per j-tile: r,z,hn x 9ks + in x 1
#define WFRAG_SHORTS (NJT * NFRAG * 512)   // 229376 shorts
#define WFC_SHORTS 4096
#define XT_OFF_BYTES ((WFRAG_SHORTS + WFC_SHORTS) * 2)        // 466944
#define WS_NEED_XT (XT_OFF_BYTES + BATCH * LSEQ * 4)          // ~16.45 MB

#define HROW 264                           // padded h row stride (shorts)
#define HBUF_S (128 * HROW)                // 33792 shorts = 67584 B per buffer
#define LDS_BYTES (2 * HBUF_S * 2)         // 135168 B

#define L2E 1.4426950408889634f
#define LN2 0.6931471805599453f

#define MFMA16(A, B, C) __builtin_amdgcn_mfma_f32_16x16x32_bf16(A, B, C, 0, 0, 0)

__device__ __forceinline__ unsigned short f2b(float f) {
  unsigned u = __float_as_uint(f);
  u += 0x7FFFu + ((u >> 16) & 1u);     // RNE bf16
  return (unsigned short)(u >> 16);
}

__device__ __forceinline__ float exp2n(float x) { float r; asm("v_exp_f32 %0, -%1" : "=v"(r) : "v"(x)); return r; }
__device__ __forceinline__ float exp2p(float x) { float r; asm("v_exp_f32 %0, %1" : "=v"(r) : "v"(x)); return r; }
__device__ __forceinline__ float rcp_(float x)  { float r; asm("v_rcp_f32 %0, %1" : "=v"(r) : "v"(x)); return r; }
__device__ __forceinline__ float log2_(float x) { float r; asm("v_log_f32 %0, %1" : "=v"(r) : "v"(x)); return r; }
__device__ __forceinline__ unsigned cvtpk(float lo, float hi) {
  unsigned r; asm("v_cvt_pk_bf16_f32 %0, %1, %2" : "=v"(r) : "v"(lo), "v"(hi)); return r;
}

// Pack W into MFMA 16x16x32 A-fragment order, UNFOLDED (no L2E in weights).
// Augmented K: k256 = x coeff, k257 = bias.
// Fragment (jt, f): f = g*9+ks (g=0 r,1 z,2 hn); f==27 unused by main.
// Element (lane, e): A-row = jt*16 + (lane&15), k = ks*32 + (lane>>4)*8 + e.
__global__ void gru_prep(const float* __restrict__ Wih, const float* __restrict__ Whh,
                         const float* __restrict__ bih, const float* __restrict__ bhh,
                         const float* __restrict__ Wfc,
                         unsigned short* __restrict__ wfrag,
                         unsigned short* __restrict__ wfc16) {
  int t = blockIdx.x * 256 + threadIdx.x;
  if (t < WFRAG_SHORTS) {
    int e = t & 7, lane = (t >> 3) & 63, fl = t >> 9;
    int f = fl % NFRAG, jt = fl / NFRAG;
    int m = lane & 15, gl = lane >> 4;
    float val = 0.f;
    if (f < 27) {
      int g = f / 9, ks = f % 9;
      int row = g * 256 + jt * 16 + m;
      int k = ks * 32 + gl * 8 + e;
      if (k < 256) val = Whh[row * 256 + k];
      else if (k == 256) val = (g == 2) ? 0.f : Wih[row];
      else if (k == 257) val = (g == 2) ? bhh[row] : (bih[row] + bhh[row]);
    }
    wfrag[t] = f2b(val);
  } else if (t < WFRAG_SHORTS + WFC_SHORTS) { // W_fc -> bf16 [16][256] row-major
    int t2 = t - WFRAG_SHORTS;
    wfc16[t2] = f2b(Wfc[t2]);
  }
}

// Tiled transpose x[B][L] -> xT[L][B] so per-step column reads are coalesced.
__global__ void x_transpose(const int* __restrict__ x, int* __restrict__ xT) {
  __shared__ int tile[32][33];
  int l0 = blockIdx.x * 32, b0 = blockIdx.y * 32;
  for (int r = threadIdx.y; r < 32; r += 8)
    tile[r][threadIdx.x] = x[(b0 + r) * LSEQ + l0 + threadIdx.x];
  __syncthreads();
  for (int r = threadIdx.y; r < 32; r += 8)
    xT[(l0 + r) * BATCH + b0 + threadIdx.x] = tile[threadIdx.x][r];
}

template <int XT>
__global__ __attribute__((amdgpu_waves_per_eu(2, 2))) __launch_bounds__(512)
void gru_main(const int* __restrict__ x, const int* __restrict__ xTr,
              const unsigned short* __restrict__ wfrag,
              const unsigned short* __restrict__ wfc16,
              const float* __restrict__ Wih, const float* __restrict__ bih,
              const float* __restrict__ bfc, float* __restrict__ out) {
  extern __shared__ unsigned short sm[];
  unsigned short* h0 = sm;                 // 67584 B
  unsigned short* h1 = sm + HBUF_S;        // 67584 B

  const int tid = threadIdx.x;
  const int lane = tid & 63;
  const int wv = tid >> 6;      // wave 0..7
  const int q = lane >> 4;      // 0..3
  const int b = lane & 15;
  const int bbase = blockIdx.x * 128;

  { // zero h0 (h1 fully written in step 0 before any read)
    unsigned int* p = (unsigned int*)h0;
#pragma unroll
    for (int r = 0; r < 33; ++r) p[tid + r * 512] = 0u;
  }

  // i_n scalar coefficients for both phases (plain scale; persistent regs)
  float win0[4], bin0[4], win1[4], bin1[4];
#pragma unroll
  for (int r = 0; r < 4; ++r) {
    int j0 = 512 + wv * 16 + q * 4 + r;
    int j1 = 512 + (wv + 8) * 16 + q * 4 + r;
    win0[r] = Wih[j0];  bin0[r] = bih[j0];
    win1[r] = Wih[j1];  bin1[r] = bih[j1];
  }
  float bfc4[4];
#pragma unroll
  for (int r = 0; r < 4; ++r) bfc4[r] = bfc[q * 4 + r];

  // per-thread LDS base offsets (all further addressing is compile-time imm)
  const int rbase = b * HROW + 8 * q;     // for B-frag reads: + bt*16*HROW + 32*ks

  float lp = 0.f;   // natural-log units
  __syncthreads();

#pragma unroll 1
  for (int i = 0; i < LSEQ; ++i) {
    const unsigned short* rd = (i & 1) ? h1 : h0;   // h_{i-1}
    unsigned short* wr = (i & 1) ? h0 : h1;         // h_i

    // launder pointers: keep per-step loads from being hoisted across steps
    unsigned long wfu = (unsigned long)wfrag;
    asm volatile("" : "+s"(wfu));
    const unsigned short* wf = (const unsigned short*)wfu;
    unsigned long wcu = (unsigned long)wfc16;
    asm volatile("" : "+s"(wcu));
    const unsigned short* wc = (const unsigned short*)wcu;

    // x inputs for this step (x_in = x[:, i-1], 0 at i==0); values 0..15 exact
    float xin8[8];
#pragma unroll
    for (int bt = 0; bt < 8; ++bt) {
      if (XT) xin8[bt] = (i > 0) ? (float)xTr[(i - 1) * BATCH + bbase + bt * 16 + b] : 0.f;
      else    xin8[bt] = (i > 0) ? (float)x[(bbase + bt * 16 + b) * LSEQ + i - 1] : 0.f;
    }

#pragma unroll 1
    for (int ph = 0; ph < 2; ++ph) {
      const int jt = wv + 8 * ph;
      const unsigned short* fb = wf + (jt * NFRAG * 64 + lane) * 8;
      const unsigned short* rdT = rd + rbase;

      // ---- issue aug + ks0..3 loads (15) ----
      s16x8 ar = *(const s16x8*)(fb + 8 * 512);
      s16x8 az = *(const s16x8*)(fb + 17 * 512);
      s16x8 ah = *(const s16x8*)(fb + 26 * 512);
      s16x8 c0r = *(const s16x8*)(fb + 0 * 512), c0z = *(const s16x8*)(fb + 9 * 512),  c0h = *(const s16x8*)(fb + 18 * 512);
      s16x8 c1r = *(const s16x8*)(fb + 1 * 512), c1z = *(const s16x8*)(fb + 10 * 512), c1h = *(const s16x8*)(fb + 19 * 512);
      s16x8 c2r = *(const s16x8*)(fb + 2 * 512), c2z = *(const s16x8*)(fb + 11 * 512), c2h = *(const s16x8*)(fb + 20 * 512);
      s16x8 c3r = *(const s16x8*)(fb + 3 * 512), c3z = *(const s16x8*)(fb + 12 * 512), c3h = *(const s16x8*)(fb + 21 * 512);

      // ---- aug-first MFMAs: init accumulators with gi + bias ----
      f32x4 aR[8], aZ[8], aH[8];
      const f32x4 Z4 = {0.f, 0.f, 0.f, 0.f};
#pragma unroll
      for (int bt = 0; bt < 8; ++bt) {
        union { unsigned u[4]; s16x8 v; } xf;
        xf.u[0] = (q == 0) ? ((__float_as_uint(xin8[bt]) >> 16) | 0x3F800000u) : 0u;
        xf.u[1] = xf.u[2] = xf.u[3] = 0u;
        aR[bt] = MFMA16(ar, xf.v, Z4);
        aZ[bt] = MFMA16(az, xf.v, Z4);
        aH[bt] = MFMA16(ah, xf.v, Z4);
      }

      // ---- issue ks4..7 loads (12) — in flight under bursts 0..3 ----
      s16x8 n0r = *(const s16x8*)(fb + 4 * 512), n0z = *(const s16x8*)(fb + 13 * 512), n0h = *(const s16x8*)(fb + 22 * 512);
      s16x8 n1r = *(const s16x8*)(fb + 5 * 512), n1z = *(const s16x8*)(fb + 14 * 512), n1h = *(const s16x8*)(fb + 23 * 512);
      s16x8 n2r = *(const s16x8*)(fb + 6 * 512), n2z = *(const s16x8*)(fb + 15 * 512), n2h = *(const s16x8*)(fb + 24 * 512);
      s16x8 n3r = *(const s16x8*)(fb + 7 * 512), n3z = *(const s16x8*)(fb + 16 * 512), n3h = *(const s16x8*)(fb + 25 * 512);

#define BURST(CR, CZ, CH, KS)                                                   \
  {                                                                             \
    _Pragma("unroll")                                                           \
    for (int bt = 0; bt < 8; ++bt) {                                            \
      const s16x8 hb = *(const s16x8*)&rdT[bt * 16 * HROW + 32 * (KS)];         \
      aR[bt] = MFMA16(CR, hb, aR[bt]);                                          \
      aZ[bt] = MFMA16(CZ, hb, aZ[bt]);                                          \
      aH[bt] = MFMA16(CH, hb, aH[bt]);                                          \
    }                                                                           \
  }
      BURST(c0r, c0z, c0h, 0)
      BURST(c1r, c1z, c1h, 1)
      BURST(c2r, c2z, c2h, 2)
      BURST(c3r, c3z, c3h, 3)
      BURST(n0r, n0z, n0h, 4)
      BURST(n1r, n1z, n1h, 5)
      BURST(n2r, n2z, n2h, 6)
      BURST(n3r, n3z, n3h, 7)
#undef BURST

      // ---- gate epilogue + direct h write ----
      const float wcA = ph ? win1[0] : win0[0], wcB = ph ? win1[1] : win0[1];
      const float wcC = ph ? win1[2] : win0[2], wcD = ph ? win1[3] : win0[3];
      const float bcA = ph ? bin1[0] : bin0[0], bcB = ph ? bin1[1] : bin0[1];
      const float bcC = ph ? bin1[2] : bin0[2], bcD = ph ? bin1[3] : bin0[3];
#pragma unroll
      for (int bt = 0; bt < 8; ++bt) {
        const int lrow = bt * 16 + b;
        const uint2 hp = *(const uint2*)&rd[lrow * HROW + 16 * jt + 4 * q];
        const float xv = xin8[bt];
        const float inr[4] = {fmaf(xv, wcA, bcA), fmaf(xv, wcB, bcB),
                              fmaf(xv, wcC, bcC), fmaf(xv, wcD, bcD)};
        const float hpv[4] = {
            __uint_as_float(hp.x << 16), __uint_as_float(hp.x & 0xFFFF0000u),
            __uint_as_float(hp.y << 16), __uint_as_float(hp.y & 0xFFFF0000u)};
        float hv[4];
#pragma unroll
        for (int r = 0; r < 4; ++r) {
          float rr = rcp_(1.f + exp2n(L2E * aR[bt][r]));   // sigmoid
          float zz = rcp_(1.f + exp2n(L2E * aZ[bt][r]));
          float y  = fmaf(rr, aH[bt][r], inr[r]);          // i_n + r*h_n
          float u  = rcp_(1.f + exp2p((2.f * L2E) * y));
          float nn = fmaf(-2.f, u, 1.f);                   // tanh
          hv[r] = fmaf(zz, hpv[r] - nn, nn);               // (1-z)*n + z*h
        }
        *(uint2*)&wr[lrow * HROW + 16 * jt + 4 * q] =
            make_uint2(cvtpk(hv[0], hv[1]), cvtpk(hv[2], hv[3]));
      }
    }

    __syncthreads();   // h_i fully visible; only barrier per step

    { // FC + log_softmax + gather; wave wv handles batch tile bt == wv
      const int lrow = wv * 16 + b;
      const int grow = bbase + lrow;
      f32x4 fa = {bfc4[0], bfc4[1], bfc4[2], bfc4[3]};
      const unsigned short* hbb = wr + lrow * HROW + 8 * q;
      const unsigned short* wcb = wc + b * 256 + q * 8;
#pragma unroll
      for (int ks = 0; ks < 8; ++ks) {
        s16x8 wfcf = *(const s16x8*)(wcb + 32 * ks);
        s16x8 hb = *(const s16x8*)(hbb + 32 * ks);
        fa = MFMA16(wfcf, hb, fa);
      }
      int tgt = XT ? xTr[i * BATCH + grow] : x[grow * LSEQ + i];
      float l0 = fa[0], l1 = fa[1], l2 = fa[2], l3 = fa[3];
      float mx = fmaxf(fmaxf(l0, l1), fmaxf(l2, l3));
      mx = fmaxf(mx, __shfl_xor(mx, 16));
      mx = fmaxf(mx, __shfl_xor(mx, 32));
      float se = exp2p(L2E * (l0 - mx)) + exp2p(L2E * (l1 - mx)) +
                 exp2p(L2E * (l2 - mx)) + exp2p(L2E * (l3 - mx));
      se += __shfl_xor(se, 16);
      se += __shfl_xor(se, 32);
      float v01 = (tgt & 1) ? l1 : l0;
      float v23 = (tgt & 1) ? l3 : l2;
      float vs = (tgt & 2) ? v23 : v01;
      float contrib = (q == (tgt >> 2)) ? vs : 0.f;
      contrib += __shfl_xor(contrib, 16);
      contrib += __shfl_xor(contrib, 32);
      lp += contrib - mx - LN2 * log2_(se);
    }
  }

  if (q == 0) out[bbase + wv * 16 + b] = lp;
}

extern "C" void kernel_launch(void* const* d_in, const int* in_sizes, int n_in,
                              void* d_out, int out_size, void* d_ws, size_t ws_size,
                              hipStream_t stream) {
  (void)in_sizes; (void)n_in; (void)out_size;
  const int*   x   = (const int*)d_in[0];
  const float* Wih = (const float*)d_in[1];
  const float* Whh = (const float*)d_in[2];
  const float* bih = (const float*)d_in[3];
  const float* bhh = (const float*)d_in[4];
  const float* Wfc = (const float*)d_in[5];
  const float* bfc = (const float*)d_in[6];
  float* out = (float*)d_out;

  unsigned short* wfrag = (unsigned short*)d_ws;
  unsigned short* wfc16 = wfrag + WFRAG_SHORTS;
  int* xT = (int*)((char*)d_ws + XT_OFF_BYTES);

  gru_prep<<<dim3(912), dim3(256), 0, stream>>>(Wih, Whh, bih, bhh, Wfc, wfrag, wfc16);

  if (ws_size >= (size_t)WS_NEED_XT) {
    x_transpose<<<dim3(LSEQ / 32, BATCH / 32), dim3(32, 8), 0, stream>>>(x, xT);
    hipFuncSetAttribute((const void*)gru_main<1>,
                        hipFuncAttributeMaxDynamicSharedMemorySize, LDS_BYTES);
    gru_main<1><<<dim3(256), dim3(512), LDS_BYTES, stream>>>(x, xT, wfrag, wfc16,
                                                             Wih, bih, bfc, out);
  } else {
    hipFuncSetAttribute((const void*)gru_main<0>,
                        hipFuncAttributeMaxDynamicSharedMemorySize, LDS_BYTES);
    gru_main<0><<<dim3(256), dim3(512), LDS_BYTES, stream>>>(x, x, wfrag, wfc16,
                                                             Wih, bih, bfc, out);
  }
}